// Round 6
// baseline (3298.372 us; speedup 1.0000x reference)
//
#include <hip/hip_runtime.h>

// LIF sim, two-phase:
//   1) lif_gemm: aS[t][b][n] = x[t][b][:] @ h1[:][n]  (f32, ascending-i fmaf,
//      bit-identical to the verified Round-5 kernel), written into d_out.
//      k-split LDS staging (32 KB) -> 5 blocks/CU -> 5 waves/SIMD.
//   2) lif_scan: sequential 500-step LIF update per batch row, f64 state,
//      aS prefetched 4 steps deep, overwrites d_out with spikes.
constexpr int BSZ = 256;
constexpr int NRN = 512;
constexpr int KIN = 512;
constexpr int TT  = 500;
constexpr int MT  = 32;               // GEMM rows per block
constexpr int KH  = 256;              // k-half

#define MAC8(r, xs, h0, h1v)                          \
    acc[r][0] = fmaf(xs, (h0).x,  acc[r][0]);         \
    acc[r][1] = fmaf(xs, (h0).y,  acc[r][1]);         \
    acc[r][2] = fmaf(xs, (h0).z,  acc[r][2]);         \
    acc[r][3] = fmaf(xs, (h0).w,  acc[r][3]);         \
    acc[r][4] = fmaf(xs, (h1v).x, acc[r][4]);         \
    acc[r][5] = fmaf(xs, (h1v).y, acc[r][5]);         \
    acc[r][6] = fmaf(xs, (h1v).z, acc[r][6]);         \
    acc[r][7] = fmaf(xs, (h1v).w, acc[r][7]);

__global__ __launch_bounds__(256, 5)
void lif_gemm(const float* __restrict__ x,
              const float* __restrict__ h1,
              float* __restrict__ out)
{
    __shared__ float xb[MT * KH];           // 32 KB x k-half tile

    const int tid = threadIdx.x;
    const int mg  = tid >> 6;               // m-group 0..3 (8 rows each)
    const int n0  = (tid & 63) * 8;         // 8 contiguous output cols
    const size_t m0 = (size_t)blockIdx.x * MT;

    float acc[8][8];
    #pragma unroll
    for (int r = 0; r < 8; ++r)
        #pragma unroll
        for (int c = 0; c < 8; ++c) acc[r][c] = 0.0f;

    for (int h = 0; h < 2; ++h) {           // k halves: i in [h*256, h*256+256)
        // stage 32 rows x 256 k of x (32 KB), coalesced float4
        #pragma unroll
        for (int it = 0; it < MT * KH / 4 / 256; ++it) {
            const int idx = it * 256 + tid;
            const int r   = idx >> 6;       // row 0..31
            const int k4  = idx & 63;       // float4 index in half
            *reinterpret_cast<float4*>(&xb[r * KH + k4 * 4]) =
                *reinterpret_cast<const float4*>(
                    x + (m0 + r) * KIN + h * KH + k4 * 4);
        }
        __syncthreads();

        for (int k4 = 0; k4 < KH / 4; ++k4) {
            float4 hv0[4], hv1[4];          // h1[4i][8n] micro-tile
            #pragma unroll
            for (int ii = 0; ii < 4; ++ii) {
                const float* hp = h1 + (size_t)(h * KH + k4 * 4 + ii) * NRN + n0;
                hv0[ii] = *reinterpret_cast<const float4*>(hp);
                hv1[ii] = *reinterpret_cast<const float4*>(hp + 4);
            }
            #pragma unroll
            for (int r = 0; r < 8; ++r) {
                const float4 xv = *reinterpret_cast<const float4*>(
                    &xb[(mg * 8 + r) * KH + k4 * 4]);   // wave-broadcast read
                MAC8(r, xv.x, hv0[0], hv1[0])           // ascending i
                MAC8(r, xv.y, hv0[1], hv1[1])
                MAC8(r, xv.z, hv0[2], hv1[2])
                MAC8(r, xv.w, hv0[3], hv1[3])
            }
        }
        __syncthreads();
    }

    #pragma unroll
    for (int r = 0; r < 8; ++r) {
        float* op = out + (m0 + mg * 8 + r) * NRN + n0;
        float4 o0 = { acc[r][0], acc[r][1], acc[r][2], acc[r][3] };
        float4 o1 = { acc[r][4], acc[r][5], acc[r][6], acc[r][7] };
        *reinterpret_cast<float4*>(op)     = o0;
        *reinterpret_cast<float4*>(op + 4) = o1;
    }
}

__global__ __launch_bounds__(512, 2)
void lif_scan(const float* __restrict__ r1,
              float* __restrict__ out)
{
    __shared__ unsigned long long smask[2][8];   // ping-pong 512-bit spike mask

    const int n  = threadIdx.x;      // neuron
    const int b  = blockIdx.x;       // batch row
    const int wv = n >> 6;
    const int ln = n & 63;
    const size_t row = (size_t)b * NRN + n;
    constexpr size_t STEP = (size_t)BSZ * NRN;

    if (n < 16) ((unsigned long long*)smask)[n] = 0ULL;

    // f64 ascending-j column sum of r1 (dense recurrent fast path)
    double csum = 0.0;
    for (int j = 0; j < KIN; ++j)
        csum += (double)r1[(size_t)j * NRN + n];

    double V = 1.0, Is = 0.0, Ir = 0.0, cnt = 0.0;
    const double steady = 0.01 * (double)n;
    constexpr double kS = 0.1, kN = 0.05, DT = 0.001;

    // aS prefetch, depth 4 (named regs -> no scratch)
    float a0 = out[0 * STEP + row];
    float a1 = out[1 * STEP + row];
    float a2 = out[2 * STEP + row];
    float a3 = out[3 * STEP + row];
    __syncthreads();

#define LIF_STEP(T, AREG)                                                     \
    {                                                                         \
        const int t_ = (T);                                                   \
        const int p_ = t_ & 1;                                                \
        unsigned long long mw[8];                                             \
        int pc = 0;                                                           \
        _Pragma("unroll")                                                     \
        for (int w = 0; w < 8; ++w) { mw[w] = smask[p_][w]; pc += __popcll(mw[w]); } \
        double aR;                                                            \
        if (pc == 512) {                                                      \
            aR = csum;                                                        \
        } else if (pc == 0) {                                                 \
            aR = 0.0;                                                         \
        } else {                                                              \
            aR = 0.0;                                                         \
            _Pragma("unroll")                                                 \
            for (int w = 0; w < 8; ++w) {                                     \
                unsigned long long m_ = mw[w];                                \
                while (m_) {                          /* ascending j */       \
                    const int j = w * 64 + __builtin_ctzll(m_);               \
                    aR += (double)r1[(size_t)j * NRN + n];                    \
                    m_ &= m_ - 1;                                             \
                }                                                             \
            }                                                                 \
        }                                                                     \
        Is = Is - kS * Is + (double)(AREG);            /* gain_syn = 1 */     \
        Ir = Ir - kS * Ir + 0.5 * aR;                  /* gain_syn_rec */     \
        double Vn = V - kN * V + DT * (Is + Ir + steady);                     \
        Vn = fmax(Vn, 0.0);                                                   \
        const bool sp = (Vn - 1.0) > 0.0;                                     \
        cnt = sp ? 2.0 : (cnt - 1.0);                  /* REFR = 2 */         \
        V = sp ? 0.0 : ((cnt <= 0.0) ? Vn : 0.0);                             \
        out[(size_t)t_ * STEP + row] = sp ? 1.0f : 0.0f;                      \
        const unsigned long long bal = __ballot(sp);                          \
        if (ln == 0) smask[p_ ^ 1][wv] = bal;                                 \
        __syncthreads();                                                      \
    }

    for (int t4 = 0; t4 < TT; t4 += 4) {
        LIF_STEP(t4 + 0, a0)
        a0 = (t4 + 4 < TT) ? out[(size_t)(t4 + 4) * STEP + row] : 0.0f;
        LIF_STEP(t4 + 1, a1)
        a1 = (t4 + 5 < TT) ? out[(size_t)(t4 + 5) * STEP + row] : 0.0f;
        LIF_STEP(t4 + 2, a2)
        a2 = (t4 + 6 < TT) ? out[(size_t)(t4 + 6) * STEP + row] : 0.0f;
        LIF_STEP(t4 + 3, a3)
        a3 = (t4 + 7 < TT) ? out[(size_t)(t4 + 7) * STEP + row] : 0.0f;
    }
#undef LIF_STEP
}

extern "C" void kernel_launch(void* const* d_in, const int* in_sizes, int n_in,
                              void* d_out, int out_size, void* d_ws, size_t ws_size,
                              hipStream_t stream) {
    const float* x  = (const float*)d_in[0];
    const float* h1 = (const float*)d_in[1];
    const float* r1 = (const float*)d_in[2];
    float* out = (float*)d_out;
    (void)d_ws; (void)ws_size; (void)in_sizes; (void)n_in; (void)out_size;

    lif_gemm<<<dim3(TT * BSZ / MT), dim3(256), 0, stream>>>(x, h1, out);
    lif_scan<<<dim3(BSZ), dim3(512), 0, stream>>>(r1, out);
}

// Round 7
// 972.009 us; speedup vs baseline: 3.3934x; 3.3934x over previous
//
#include <hip/hip_runtime.h>

// LIF sim, two-phase:
//   1) lif_gemm: aS[t][b][n] = x[t][b][:] @ h1[:][n]  (f32, ascending-i fmaf,
//      bit-identical decision path to the verified Round-5 kernel), into d_out.
//      32 KB k-split staging; launch_bounds(256,4): VGPR cap 128 (no spill!),
//      4 blocks/CU guaranteed.
//   2) lif_scan: sequential 500-step LIF update per batch row, f64 state,
//      aS prefetched 4 steps deep, overwrites d_out with spikes.
constexpr int BSZ = 256;
constexpr int NRN = 512;
constexpr int KIN = 512;
constexpr int TT  = 500;
constexpr int MT  = 32;               // GEMM rows per block
constexpr int KH  = 256;              // k-half

#define MAC8(r, xs, h0, h1v)                          \
    acc[r][0] = fmaf(xs, (h0).x,  acc[r][0]);         \
    acc[r][1] = fmaf(xs, (h0).y,  acc[r][1]);         \
    acc[r][2] = fmaf(xs, (h0).z,  acc[r][2]);         \
    acc[r][3] = fmaf(xs, (h0).w,  acc[r][3]);         \
    acc[r][4] = fmaf(xs, (h1v).x, acc[r][4]);         \
    acc[r][5] = fmaf(xs, (h1v).y, acc[r][5]);         \
    acc[r][6] = fmaf(xs, (h1v).z, acc[r][6]);         \
    acc[r][7] = fmaf(xs, (h1v).w, acc[r][7]);

__global__ __launch_bounds__(256, 4)
void lif_gemm(const float* __restrict__ x,
              const float* __restrict__ h1,
              float* __restrict__ out)
{
    __shared__ float xb[MT * KH];           // 32 KB x k-half tile

    const int tid = threadIdx.x;
    const int mg  = tid >> 6;               // m-group 0..3 (8 rows each)
    const int n0  = (tid & 63) * 8;         // 8 contiguous output cols
    const size_t m0 = (size_t)blockIdx.x * MT;

    float acc[8][8];
    #pragma unroll
    for (int r = 0; r < 8; ++r)
        #pragma unroll
        for (int c = 0; c < 8; ++c) acc[r][c] = 0.0f;

    for (int h = 0; h < 2; ++h) {           // k halves: i in [h*256, h*256+256)
        // stage 32 rows x 256 k of x (32 KB), coalesced float4
        #pragma unroll
        for (int it = 0; it < MT * KH / 4 / 256; ++it) {
            const int idx = it * 256 + tid;
            const int r   = idx >> 6;       // row 0..31
            const int k4  = idx & 63;       // float4 index in half
            *reinterpret_cast<float4*>(&xb[r * KH + k4 * 4]) =
                *reinterpret_cast<const float4*>(
                    x + (m0 + r) * KIN + h * KH + k4 * 4);
        }
        __syncthreads();

        for (int k4 = 0; k4 < KH / 4; ++k4) {
            float4 hv0[4], hv1[4];          // h1[4i][8n] micro-tile
            #pragma unroll
            for (int ii = 0; ii < 4; ++ii) {
                const float* hp = h1 + (size_t)(h * KH + k4 * 4 + ii) * NRN + n0;
                hv0[ii] = *reinterpret_cast<const float4*>(hp);
                hv1[ii] = *reinterpret_cast<const float4*>(hp + 4);
            }
            #pragma unroll
            for (int r = 0; r < 8; ++r) {
                const float4 xv = *reinterpret_cast<const float4*>(
                    &xb[(mg * 8 + r) * KH + k4 * 4]);   // wave-broadcast read
                MAC8(r, xv.x, hv0[0], hv1[0])           // ascending i
                MAC8(r, xv.y, hv0[1], hv1[1])
                MAC8(r, xv.z, hv0[2], hv1[2])
                MAC8(r, xv.w, hv0[3], hv1[3])
            }
        }
        __syncthreads();
    }

    #pragma unroll
    for (int r = 0; r < 8; ++r) {
        float* op = out + (m0 + mg * 8 + r) * NRN + n0;
        float4 o0 = { acc[r][0], acc[r][1], acc[r][2], acc[r][3] };
        float4 o1 = { acc[r][4], acc[r][5], acc[r][6], acc[r][7] };
        *reinterpret_cast<float4*>(op)     = o0;
        *reinterpret_cast<float4*>(op + 4) = o1;
    }
}

__global__ __launch_bounds__(512, 2)
void lif_scan(const float* __restrict__ r1,
              float* __restrict__ out)
{
    __shared__ unsigned long long smask[2][8];   // ping-pong 512-bit spike mask

    const int n  = threadIdx.x;      // neuron
    const int b  = blockIdx.x;       // batch row
    const int wv = n >> 6;
    const int ln = n & 63;
    const size_t row = (size_t)b * NRN + n;
    constexpr size_t STEP = (size_t)BSZ * NRN;

    if (n < 16) ((unsigned long long*)smask)[n] = 0ULL;

    // f64 ascending-j column sum of r1 (dense recurrent fast path)
    double csum = 0.0;
    for (int j = 0; j < KIN; ++j)
        csum += (double)r1[(size_t)j * NRN + n];

    double V = 1.0, Is = 0.0, Ir = 0.0, cnt = 0.0;
    const double steady = 0.01 * (double)n;
    constexpr double kS = 0.1, kN = 0.05, DT = 0.001;

    // aS prefetch, depth 4 (named regs -> no scratch)
    float a0 = out[0 * STEP + row];
    float a1 = out[1 * STEP + row];
    float a2 = out[2 * STEP + row];
    float a3 = out[3 * STEP + row];
    __syncthreads();

#define LIF_STEP(T, AREG)                                                     \
    {                                                                         \
        const int t_ = (T);                                                   \
        const int p_ = t_ & 1;                                                \
        unsigned long long mw[8];                                             \
        int pc = 0;                                                           \
        _Pragma("unroll")                                                     \
        for (int w = 0; w < 8; ++w) { mw[w] = smask[p_][w]; pc += __popcll(mw[w]); } \
        double aR;                                                            \
        if (pc == 512) {                                                      \
            aR = csum;                                                        \
        } else if (pc == 0) {                                                 \
            aR = 0.0;                                                         \
        } else {                                                              \
            aR = 0.0;                                                         \
            _Pragma("unroll")                                                 \
            for (int w = 0; w < 8; ++w) {                                     \
                unsigned long long m_ = mw[w];                                \
                while (m_) {                          /* ascending j */       \
                    const int j = w * 64 + __builtin_ctzll(m_);               \
                    aR += (double)r1[(size_t)j * NRN + n];                    \
                    m_ &= m_ - 1;                                             \
                }                                                             \
            }                                                                 \
        }                                                                     \
        Is = Is - kS * Is + (double)(AREG);            /* gain_syn = 1 */     \
        Ir = Ir - kS * Ir + 0.5 * aR;                  /* gain_syn_rec */     \
        double Vn = V - kN * V + DT * (Is + Ir + steady);                     \
        Vn = fmax(Vn, 0.0);                                                   \
        const bool sp = (Vn - 1.0) > 0.0;                                     \
        cnt = sp ? 2.0 : (cnt - 1.0);                  /* REFR = 2 */         \
        V = sp ? 0.0 : ((cnt <= 0.0) ? Vn : 0.0);                             \
        out[(size_t)t_ * STEP + row] = sp ? 1.0f : 0.0f;                      \
        const unsigned long long bal = __ballot(sp);                          \
        if (ln == 0) smask[p_ ^ 1][wv] = bal;                                 \
        __syncthreads();                                                      \
    }

    for (int t4 = 0; t4 < TT; t4 += 4) {
        LIF_STEP(t4 + 0, a0)
        a0 = (t4 + 4 < TT) ? out[(size_t)(t4 + 4) * STEP + row] : 0.0f;
        LIF_STEP(t4 + 1, a1)
        a1 = (t4 + 5 < TT) ? out[(size_t)(t4 + 5) * STEP + row] : 0.0f;
        LIF_STEP(t4 + 2, a2)
        a2 = (t4 + 6 < TT) ? out[(size_t)(t4 + 6) * STEP + row] : 0.0f;
        LIF_STEP(t4 + 3, a3)
        a3 = (t4 + 7 < TT) ? out[(size_t)(t4 + 7) * STEP + row] : 0.0f;
    }
#undef LIF_STEP
}

extern "C" void kernel_launch(void* const* d_in, const int* in_sizes, int n_in,
                              void* d_out, int out_size, void* d_ws, size_t ws_size,
                              hipStream_t stream) {
    const float* x  = (const float*)d_in[0];
    const float* h1 = (const float*)d_in[1];
    const float* r1 = (const float*)d_in[2];
    float* out = (float*)d_out;
    (void)d_ws; (void)ws_size; (void)in_sizes; (void)n_in; (void)out_size;

    lif_gemm<<<dim3(TT * BSZ / MT), dim3(256), 0, stream>>>(x, h1, out);
    lif_scan<<<dim3(BSZ), dim3(512), 0, stream>>>(r1, out);
}

// Round 8
// 502.419 us; speedup vs baseline: 6.5650x; 1.9347x over previous
//
#include <hip/hip_runtime.h>

// LIF sim, two-phase:
//   1) lif_gemm: aS = X[128000x512] @ H[512x512] via bf16 4-way-split MFMA
//      (xh+xl)(hh+hl), f32 accumulate — error class below the f32 chain that
//      already produced zero spike flips. Written into d_out.
//   2) lif_scan: verified sequential 500-step LIF scan (f64 state), reads aS
//      from d_out, overwrites with spikes. Unchanged from Round 5/7.
typedef __attribute__((ext_vector_type(8))) short short8;
typedef __attribute__((ext_vector_type(4))) float f32x4;

constexpr int BSZ = 256;
constexpr int NRN = 512;
constexpr int KIN = 512;
constexpr int TT  = 500;
constexpr int BM  = 128;   // m-tile (rows of x)
constexpr int BN  = 128;   // n-tile (neuron cols)
constexpr int KT  = 32;    // k-tile

__device__ __forceinline__ unsigned short bf16rne(float f) {
    unsigned u = __float_as_uint(f);
    u += 0x7FFFu + ((u >> 16) & 1u);
    return (unsigned short)(u >> 16);
}
__device__ __forceinline__ float bf16f(unsigned short s) {
    return __uint_as_float(((unsigned)s) << 16);
}

__global__ __launch_bounds__(256)
void lif_gemm(const float* __restrict__ x,
              const float* __restrict__ h1,
              float* __restrict__ out)
{
    // bf16 tiles, XOR-swizzled (byte ^= ((row>>1)&3)<<4): 4 x 8 KB = 32 KB
    __shared__ short AhS[BM * KT], AlS[BM * KT], BhS[BN * KT], BlS[BN * KT];

    const int tid  = threadIdx.x;
    const int l    = tid & 63;
    const int w    = tid >> 6;           // wave 0..3
    const int wm   = (w & 1) * 64;       // wave m-offset
    const int wn   = (w >> 1) * 64;      // wave n-offset
    const int lrow = l & 15;
    const int loct = l >> 4;             // k-octet 0..3
    const size_t m0 = (size_t)(blockIdx.x >> 2) * BM;
    const int    n0 = (blockIdx.x & 3) * BN;

    f32x4 acc[4][4];
    #pragma unroll
    for (int i = 0; i < 4; ++i)
        #pragma unroll
        for (int j = 0; j < 4; ++j) acc[i][j] = (f32x4)0.0f;

    for (int kt = 0; kt < KIN / KT; ++kt) {
        // ---- stage A: x[m0..m0+128][kt*32..+32] -> bf16 split, swizzled ----
        #pragma unroll
        for (int u4 = 0; u4 < 4; ++u4) {
            const int u = u4 * 256 + tid;         // 0..1023
            const int row = u >> 3, slot = u & 7; // row 0..127, float4 slot 0..7
            const float4 xv = *reinterpret_cast<const float4*>(
                x + (m0 + row) * KIN + kt * KT + slot * 4);
            unsigned long long hb = 0, lb = 0;
            const float vv[4] = { xv.x, xv.y, xv.z, xv.w };
            #pragma unroll
            for (int i = 0; i < 4; ++i) {
                const unsigned short h  = bf16rne(vv[i]);
                const unsigned short lo = bf16rne(vv[i] - bf16f(h));
                hb |= (unsigned long long)h  << (16 * i);
                lb |= (unsigned long long)lo << (16 * i);
            }
            const int byte = (row * 64 + slot * 8) ^ (((row >> 1) & 3) << 4);
            *reinterpret_cast<unsigned long long*>((char*)AhS + byte) = hb;
            *reinterpret_cast<unsigned long long*>((char*)AlS + byte) = lb;
        }
        // ---- stage B: h1[kt*32..+32][n0..n0+128] transposed -> [n][k] ----
        #pragma unroll
        for (int u2 = 0; u2 < 2; ++u2) {
            const int u = u2 * 256 + tid;          // 0..511
            const int nl = u & 127, koct = u >> 7; // n-local, k-octet
            short8 hh, hl;
            #pragma unroll
            for (int i = 0; i < 8; ++i) {          // coalesced across nl
                const float v = h1[(size_t)(kt * KT + koct * 8 + i) * NRN + n0 + nl];
                const unsigned short h = bf16rne(v);
                hh[i] = (short)h;
                hl[i] = (short)bf16rne(v - bf16f(h));
            }
            const int byte = (nl * 64 + koct * 16) ^ (((nl >> 1) & 3) << 4);
            *reinterpret_cast<short8*>((char*)BhS + byte) = hh;
            *reinterpret_cast<short8*>((char*)BlS + byte) = hl;
        }
        __syncthreads();

        // ---- fragment loads (ds_read_b128, 2-way conflict = free) ----
        short8 ah[4], al[4], bh[4], bl[4];
        #pragma unroll
        for (int mi = 0; mi < 4; ++mi) {
            const int row  = wm + mi * 16 + lrow;
            const int byte = (row * 64 + loct * 16) ^ (((row >> 1) & 3) << 4);
            ah[mi] = *reinterpret_cast<const short8*>((const char*)AhS + byte);
            al[mi] = *reinterpret_cast<const short8*>((const char*)AlS + byte);
        }
        #pragma unroll
        for (int ni = 0; ni < 4; ++ni) {
            const int nn   = wn + ni * 16 + lrow;
            const int byte = (nn * 64 + loct * 16) ^ (((nn >> 1) & 3) << 4);
            bh[ni] = *reinterpret_cast<const short8*>((const char*)BhS + byte);
            bl[ni] = *reinterpret_cast<const short8*>((const char*)BlS + byte);
        }

        // ---- 64 MFMA: 4 split products accumulate into same acc ----
        #pragma unroll
        for (int mi = 0; mi < 4; ++mi)
            #pragma unroll
            for (int ni = 0; ni < 4; ++ni) {
                acc[mi][ni] = __builtin_amdgcn_mfma_f32_16x16x32_bf16(ah[mi], bh[ni], acc[mi][ni], 0, 0, 0);
                acc[mi][ni] = __builtin_amdgcn_mfma_f32_16x16x32_bf16(ah[mi], bl[ni], acc[mi][ni], 0, 0, 0);
                acc[mi][ni] = __builtin_amdgcn_mfma_f32_16x16x32_bf16(al[mi], bh[ni], acc[mi][ni], 0, 0, 0);
                acc[mi][ni] = __builtin_amdgcn_mfma_f32_16x16x32_bf16(al[mi], bl[ni], acc[mi][ni], 0, 0, 0);
            }
        __syncthreads();
    }

    // ---- epilogue: C/D layout col=lane&15, row=(lane>>4)*4+j (m89-verified) ----
    #pragma unroll
    for (int mi = 0; mi < 4; ++mi)
        #pragma unroll
        for (int j = 0; j < 4; ++j) {
            const size_t row = m0 + wm + mi * 16 + loct * 4 + j;
            float* op = out + row * NRN + n0 + wn + lrow;
            #pragma unroll
            for (int ni = 0; ni < 4; ++ni)
                op[ni * 16] = acc[mi][ni][j];
        }
}

__global__ __launch_bounds__(512, 2)
void lif_scan(const float* __restrict__ r1,
              float* __restrict__ out)
{
    __shared__ unsigned long long smask[2][8];   // ping-pong 512-bit spike mask

    const int n  = threadIdx.x;      // neuron
    const int b  = blockIdx.x;       // batch row
    const int wv = n >> 6;
    const int ln = n & 63;
    const size_t row = (size_t)b * NRN + n;
    constexpr size_t STEP = (size_t)BSZ * NRN;

    if (n < 16) ((unsigned long long*)smask)[n] = 0ULL;

    // f64 ascending-j column sum of r1 (dense recurrent fast path)
    double csum = 0.0;
    for (int j = 0; j < KIN; ++j)
        csum += (double)r1[(size_t)j * NRN + n];

    double V = 1.0, Is = 0.0, Ir = 0.0, cnt = 0.0;
    const double steady = 0.01 * (double)n;
    constexpr double kS = 0.1, kN = 0.05, DT = 0.001;

    // aS prefetch, depth 4 (named regs -> no scratch)
    float a0 = out[0 * STEP + row];
    float a1 = out[1 * STEP + row];
    float a2 = out[2 * STEP + row];
    float a3 = out[3 * STEP + row];
    __syncthreads();

#define LIF_STEP(T, AREG)                                                     \
    {                                                                         \
        const int t_ = (T);                                                   \
        const int p_ = t_ & 1;                                                \
        unsigned long long mw[8];                                             \
        int pc = 0;                                                           \
        _Pragma("unroll")                                                     \
        for (int w = 0; w < 8; ++w) { mw[w] = smask[p_][w]; pc += __popcll(mw[w]); } \
        double aR;                                                            \
        if (pc == 512) {                                                      \
            aR = csum;                                                        \
        } else if (pc == 0) {                                                 \
            aR = 0.0;                                                         \
        } else {                                                              \
            aR = 0.0;                                                         \
            _Pragma("unroll")                                                 \
            for (int w = 0; w < 8; ++w) {                                     \
                unsigned long long m_ = mw[w];                                \
                while (m_) {                          /* ascending j */       \
                    const int j = w * 64 + __builtin_ctzll(m_);               \
                    aR += (double)r1[(size_t)j * NRN + n];                    \
                    m_ &= m_ - 1;                                             \
                }                                                             \
            }                                                                 \
        }                                                                     \
        Is = Is - kS * Is + (double)(AREG);            /* gain_syn = 1 */     \
        Ir = Ir - kS * Ir + 0.5 * aR;                  /* gain_syn_rec */     \
        double Vn = V - kN * V + DT * (Is + Ir + steady);                     \
        Vn = fmax(Vn, 0.0);                                                   \
        const bool sp = (Vn - 1.0) > 0.0;                                     \
        cnt = sp ? 2.0 : (cnt - 1.0);                  /* REFR = 2 */         \
        V = sp ? 0.0 : ((cnt <= 0.0) ? Vn : 0.0);                             \
        out[(size_t)t_ * STEP + row] = sp ? 1.0f : 0.0f;                      \
        const unsigned long long bal = __ballot(sp);                          \
        if (ln == 0) smask[p_ ^ 1][wv] = bal;                                 \
        __syncthreads();                                                      \
    }

    for (int t4 = 0; t4 < TT; t4 += 4) {
        LIF_STEP(t4 + 0, a0)
        a0 = (t4 + 4 < TT) ? out[(size_t)(t4 + 4) * STEP + row] : 0.0f;
        LIF_STEP(t4 + 1, a1)
        a1 = (t4 + 5 < TT) ? out[(size_t)(t4 + 5) * STEP + row] : 0.0f;
        LIF_STEP(t4 + 2, a2)
        a2 = (t4 + 6 < TT) ? out[(size_t)(t4 + 6) * STEP + row] : 0.0f;
        LIF_STEP(t4 + 3, a3)
        a3 = (t4 + 7 < TT) ? out[(size_t)(t4 + 7) * STEP + row] : 0.0f;
    }
#undef LIF_STEP
}

extern "C" void kernel_launch(void* const* d_in, const int* in_sizes, int n_in,
                              void* d_out, int out_size, void* d_ws, size_t ws_size,
                              hipStream_t stream) {
    const float* x  = (const float*)d_in[0];
    const float* h1 = (const float*)d_in[1];
    const float* r1 = (const float*)d_in[2];
    float* out = (float*)d_out;
    (void)d_ws; (void)ws_size; (void)in_sizes; (void)n_in; (void)out_size;

    lif_gemm<<<dim3((TT * BSZ / BM) * (NRN / BN)), dim3(256), 0, stream>>>(x, h1, out);
    lif_scan<<<dim3(BSZ), dim3(512), 0, stream>>>(r1, out);
}

// Round 9
// 468.676 us; speedup vs baseline: 7.0376x; 1.0720x over previous
//
#include <hip/hip_runtime.h>

// LIF sim, three-phase:
//   0) split_h: pre-split h1 into bf16 hi/lo planes, stored in d_ws already in
//      the gemm's swizzled B-LDS image ([kt][nb] 8KB chunks). Runs every call.
//   1) lif_gemm<true>: aS = X @ H via bf16 4-way-split MFMA, f32 accumulate.
//      B staging = linear 8KB copy from d_ws (no conversion). XCD-chunked
//      grid swizzle so all 4 n-blocks of an m-tile share one L2.
//      (<false> = Round-8 in-kernel B conversion fallback if ws too small.)
//   2) lif_scan: verified sequential 500-step LIF scan (f64 state), unchanged.
typedef __attribute__((ext_vector_type(8))) short short8;
typedef __attribute__((ext_vector_type(4))) float f32x4;

constexpr int BSZ = 256;
constexpr int NRN = 512;
constexpr int KIN = 512;
constexpr int TT  = 500;
constexpr int BM  = 128;   // m-tile (rows of x)
constexpr int BN  = 128;   // n-tile (neuron cols)
constexpr int KT  = 32;    // k-tile
constexpr int NBLK = (TT * BSZ / BM) * (NRN / BN);   // 4000
constexpr size_t WS_NEED = (size_t)2 * KIN * NRN * sizeof(unsigned short); // 1 MB

__device__ __forceinline__ unsigned short bf16rne(float f) {
    unsigned u = __float_as_uint(f);
    u += 0x7FFFu + ((u >> 16) & 1u);
    return (unsigned short)(u >> 16);
}
__device__ __forceinline__ float bf16f(unsigned short s) {
    return __uint_as_float(((unsigned)s) << 16);
}

// h1[k][n] -> hi/lo bf16 planes, laid out as the gemm's B-LDS image:
// chunk (kt*4+nb) of 8192 B; within: byte = ((nl*64+koct*16) ^ (((nl>>1)&3)<<4)) + 2*i
__global__ __launch_bounds__(512)
void split_h(const float* __restrict__ h1,
             unsigned short* __restrict__ wsH,
             unsigned short* __restrict__ wsL)
{
    const int k = blockIdx.x;          // 0..511
    const int n = threadIdx.x;         // 0..511 (coalesced read)
    const float v = h1[(size_t)k * NRN + n];
    const unsigned short h  = bf16rne(v);
    const unsigned short lo = bf16rne(v - bf16f(h));
    const int kt = k >> 5, koct = (k >> 3) & 3, i = k & 7;
    const int nb = n >> 7, nl = n & 127;
    const int byte = (kt * 4 + nb) * 8192 +
                     ((nl * 64 + koct * 16) ^ (((nl >> 1) & 3) << 4)) + i * 2;
    *reinterpret_cast<unsigned short*>((char*)wsH + byte) = h;
    *reinterpret_cast<unsigned short*>((char*)wsL + byte) = lo;
}

template<bool PS>
__global__ __launch_bounds__(256)
void lif_gemm(const float* __restrict__ x,
              const float* __restrict__ h1,
              const unsigned short* __restrict__ wsH,
              const unsigned short* __restrict__ wsL,
              float* __restrict__ out)
{
    // bf16 tiles, XOR-swizzled (byte ^= ((row>>1)&3)<<4): 4 x 8 KB = 32 KB
    __shared__ short AhS[BM * KT], AlS[BM * KT], BhS[BN * KT], BlS[BN * KT];

    const int tid  = threadIdx.x;
    const int l    = tid & 63;
    const int w    = tid >> 6;           // wave 0..3
    const int wm   = (w & 1) * 64;       // wave m-offset
    const int wn   = (w >> 1) * 64;      // wave n-offset
    const int lrow = l & 15;
    const int loct = l >> 4;             // k-octet 0..3

    // XCD-chunked bijective swizzle: 4000 = 8 x 500, 500 % 4 == 0 so the
    // 4 n-blocks of each m-tile stay inside one XCD's chunk (shared L2).
    const int nid = (blockIdx.x & 7) * (NBLK / 8) + (blockIdx.x >> 3);
    const size_t m0 = (size_t)(nid >> 2) * BM;
    const int    nb = nid & 3;
    const int    n0 = nb * BN;

    f32x4 acc[4][4];
    #pragma unroll
    for (int i = 0; i < 4; ++i)
        #pragma unroll
        for (int j = 0; j < 4; ++j) acc[i][j] = (f32x4)0.0f;

    for (int kt = 0; kt < KIN / KT; ++kt) {
        // ---- stage A: x[m0..m0+128][kt*32..+32] -> bf16 split, swizzled ----
        #pragma unroll
        for (int u4 = 0; u4 < 4; ++u4) {
            const int u = u4 * 256 + tid;         // 0..1023
            const int row = u >> 3, slot = u & 7; // row 0..127, float4 slot 0..7
            const float4 xv = *reinterpret_cast<const float4*>(
                x + (m0 + row) * KIN + kt * KT + slot * 4);
            unsigned long long hb = 0, lb = 0;
            const float vv[4] = { xv.x, xv.y, xv.z, xv.w };
            #pragma unroll
            for (int i = 0; i < 4; ++i) {
                const unsigned short h  = bf16rne(vv[i]);
                const unsigned short lo = bf16rne(vv[i] - bf16f(h));
                hb |= (unsigned long long)h  << (16 * i);
                lb |= (unsigned long long)lo << (16 * i);
            }
            const int byte = (row * 64 + slot * 8) ^ (((row >> 1) & 3) << 4);
            *reinterpret_cast<unsigned long long*>((char*)AhS + byte) = hb;
            *reinterpret_cast<unsigned long long*>((char*)AlS + byte) = lb;
        }
        // ---- stage B ----
        if (PS) {
            // linear 8 KB copies from pre-split image (layout already swizzled)
            const float4* sH = reinterpret_cast<const float4*>(
                (const char*)wsH + (kt * 4 + nb) * 8192) + tid * 2;
            const float4* sL = reinterpret_cast<const float4*>(
                (const char*)wsL + (kt * 4 + nb) * 8192) + tid * 2;
            float4* dH = reinterpret_cast<float4*>((char*)BhS + tid * 32);
            float4* dL = reinterpret_cast<float4*>((char*)BlS + tid * 32);
            dH[0] = sH[0]; dH[1] = sH[1];
            dL[0] = sL[0]; dL[1] = sL[1];
        } else {
            #pragma unroll
            for (int u2 = 0; u2 < 2; ++u2) {
                const int u = u2 * 256 + tid;          // 0..511
                const int nl = u & 127, koct = u >> 7; // n-local, k-octet
                short8 hh, hl;
                #pragma unroll
                for (int i = 0; i < 8; ++i) {          // coalesced across nl
                    const float v = h1[(size_t)(kt * KT + koct * 8 + i) * NRN + n0 + nl];
                    const unsigned short h = bf16rne(v);
                    hh[i] = (short)h;
                    hl[i] = (short)bf16rne(v - bf16f(h));
                }
                const int byte = (nl * 64 + koct * 16) ^ (((nl >> 1) & 3) << 4);
                *reinterpret_cast<short8*>((char*)BhS + byte) = hh;
                *reinterpret_cast<short8*>((char*)BlS + byte) = hl;
            }
        }
        __syncthreads();

        // ---- fragment loads (ds_read_b128, 2-way conflict = free) ----
        short8 ah[4], al[4], bh[4], bl[4];
        #pragma unroll
        for (int mi = 0; mi < 4; ++mi) {
            const int row  = wm + mi * 16 + lrow;
            const int byte = (row * 64 + loct * 16) ^ (((row >> 1) & 3) << 4);
            ah[mi] = *reinterpret_cast<const short8*>((const char*)AhS + byte);
            al[mi] = *reinterpret_cast<const short8*>((const char*)AlS + byte);
        }
        #pragma unroll
        for (int ni = 0; ni < 4; ++ni) {
            const int nn   = wn + ni * 16 + lrow;
            const int byte = (nn * 64 + loct * 16) ^ (((nn >> 1) & 3) << 4);
            bh[ni] = *reinterpret_cast<const short8*>((const char*)BhS + byte);
            bl[ni] = *reinterpret_cast<const short8*>((const char*)BlS + byte);
        }

        // ---- 64 MFMA: 4 split products accumulate into same acc ----
        #pragma unroll
        for (int mi = 0; mi < 4; ++mi)
            #pragma unroll
            for (int ni = 0; ni < 4; ++ni) {
                acc[mi][ni] = __builtin_amdgcn_mfma_f32_16x16x32_bf16(ah[mi], bh[ni], acc[mi][ni], 0, 0, 0);
                acc[mi][ni] = __builtin_amdgcn_mfma_f32_16x16x32_bf16(ah[mi], bl[ni], acc[mi][ni], 0, 0, 0);
                acc[mi][ni] = __builtin_amdgcn_mfma_f32_16x16x32_bf16(al[mi], bh[ni], acc[mi][ni], 0, 0, 0);
                acc[mi][ni] = __builtin_amdgcn_mfma_f32_16x16x32_bf16(al[mi], bl[ni], acc[mi][ni], 0, 0, 0);
            }
        __syncthreads();
    }

    // ---- epilogue: C/D layout col=lane&15, row=(lane>>4)*4+j (m89-verified) ----
    #pragma unroll
    for (int mi = 0; mi < 4; ++mi)
        #pragma unroll
        for (int j = 0; j < 4; ++j) {
            const size_t row = m0 + wm + mi * 16 + loct * 4 + j;
            float* op = out + row * NRN + n0 + wn + lrow;
            #pragma unroll
            for (int ni = 0; ni < 4; ++ni)
                op[ni * 16] = acc[mi][ni][j];
        }
}

__global__ __launch_bounds__(512, 2)
void lif_scan(const float* __restrict__ r1,
              float* __restrict__ out)
{
    __shared__ unsigned long long smask[2][8];   // ping-pong 512-bit spike mask

    const int n  = threadIdx.x;      // neuron
    const int b  = blockIdx.x;       // batch row
    const int wv = n >> 6;
    const int ln = n & 63;
    const size_t row = (size_t)b * NRN + n;
    constexpr size_t STEP = (size_t)BSZ * NRN;

    if (n < 16) ((unsigned long long*)smask)[n] = 0ULL;

    // f64 ascending-j column sum of r1 (dense recurrent fast path)
    double csum = 0.0;
    for (int j = 0; j < KIN; ++j)
        csum += (double)r1[(size_t)j * NRN + n];

    double V = 1.0, Is = 0.0, Ir = 0.0, cnt = 0.0;
    const double steady = 0.01 * (double)n;
    constexpr double kS = 0.1, kN = 0.05, DT = 0.001;

    // aS prefetch, depth 4 (named regs -> no scratch)
    float a0 = out[0 * STEP + row];
    float a1 = out[1 * STEP + row];
    float a2 = out[2 * STEP + row];
    float a3 = out[3 * STEP + row];
    __syncthreads();

#define LIF_STEP(T, AREG)                                                     \
    {                                                                         \
        const int t_ = (T);                                                   \
        const int p_ = t_ & 1;                                                \
        unsigned long long mw[8];                                             \
        int pc = 0;                                                           \
        _Pragma("unroll")                                                     \
        for (int w = 0; w < 8; ++w) { mw[w] = smask[p_][w]; pc += __popcll(mw[w]); } \
        double aR;                                                            \
        if (pc == 512) {                                                      \
            aR = csum;                                                        \
        } else if (pc == 0) {                                                 \
            aR = 0.0;                                                         \
        } else {                                                              \
            aR = 0.0;                                                         \
            _Pragma("unroll")                                                 \
            for (int w = 0; w < 8; ++w) {                                     \
                unsigned long long m_ = mw[w];                                \
                while (m_) {                          /* ascending j */       \
                    const int j = w * 64 + __builtin_ctzll(m_);               \
                    aR += (double)r1[(size_t)j * NRN + n];                    \
                    m_ &= m_ - 1;                                             \
                }                                                             \
            }                                                                 \
        }                                                                     \
        Is = Is - kS * Is + (double)(AREG);            /* gain_syn = 1 */     \
        Ir = Ir - kS * Ir + 0.5 * aR;                  /* gain_syn_rec */     \
        double Vn = V - kN * V + DT * (Is + Ir + steady);                     \
        Vn = fmax(Vn, 0.0);                                                   \
        const bool sp = (Vn - 1.0) > 0.0;                                     \
        cnt = sp ? 2.0 : (cnt - 1.0);                  /* REFR = 2 */         \
        V = sp ? 0.0 : ((cnt <= 0.0) ? Vn : 0.0);                             \
        out[(size_t)t_ * STEP + row] = sp ? 1.0f : 0.0f;                      \
        const unsigned long long bal = __ballot(sp);                          \
        if (ln == 0) smask[p_ ^ 1][wv] = bal;                                 \
        __syncthreads();                                                      \
    }

    for (int t4 = 0; t4 < TT; t4 += 4) {
        LIF_STEP(t4 + 0, a0)
        a0 = (t4 + 4 < TT) ? out[(size_t)(t4 + 4) * STEP + row] : 0.0f;
        LIF_STEP(t4 + 1, a1)
        a1 = (t4 + 5 < TT) ? out[(size_t)(t4 + 5) * STEP + row] : 0.0f;
        LIF_STEP(t4 + 2, a2)
        a2 = (t4 + 6 < TT) ? out[(size_t)(t4 + 6) * STEP + row] : 0.0f;
        LIF_STEP(t4 + 3, a3)
        a3 = (t4 + 7 < TT) ? out[(size_t)(t4 + 7) * STEP + row] : 0.0f;
    }
#undef LIF_STEP
}

extern "C" void kernel_launch(void* const* d_in, const int* in_sizes, int n_in,
                              void* d_out, int out_size, void* d_ws, size_t ws_size,
                              hipStream_t stream) {
    const float* x  = (const float*)d_in[0];
    const float* h1 = (const float*)d_in[1];
    const float* r1 = (const float*)d_in[2];
    float* out = (float*)d_out;
    (void)in_sizes; (void)n_in; (void)out_size;

    if (ws_size >= WS_NEED) {
        unsigned short* wsH = (unsigned short*)d_ws;
        unsigned short* wsL = wsH + (size_t)KIN * NRN;
        split_h<<<dim3(KIN), dim3(NRN), 0, stream>>>(h1, wsH, wsL);
        lif_gemm<true><<<dim3(NBLK), dim3(256), 0, stream>>>(x, h1, wsH, wsL, out);
    } else {
        lif_gemm<false><<<dim3(NBLK), dim3(256), 0, stream>>>(x, h1, nullptr, nullptr, out);
    }
    lif_scan<<<dim3(BSZ), dim3(512), 0, stream>>>(r1, out);
}